// Round 19
// baseline (187.272 us; speedup 1.0000x reference)
//
#include <hip/hip_runtime.h>
#include <hip/hip_bf16.h>

#define B_ 4
#define T_ 2048
#define C_ 1024
#define H_ 16
#define HD_ 64
#define M_ (B_*T_)        // 8192 rows
#define N3_ (3*C_)        // 3072
#define QKVSZ (B_*H_*T_*HD_)  // 8388608 elems per tensor
#define QSCALE 0.1803368801f  // 0.125 * log2(e)

typedef unsigned short u16;
typedef unsigned int u32;
typedef __attribute__((ext_vector_type(8))) __bf16 bf16x8;
typedef __attribute__((ext_vector_type(4))) float f32x4;
typedef __attribute__((ext_vector_type(16))) float f32x16;
typedef __attribute__((ext_vector_type(2))) int i32x2;
typedef __attribute__((ext_vector_type(4))) u32 u32x4;
typedef const __attribute__((address_space(1))) void* gptr_t;
typedef __attribute__((address_space(3))) void* sptr_t;

__device__ __forceinline__ u16 f2b(float f) {
  __hip_bfloat16 h = __float2bfloat16(f);
  return __builtin_bit_cast(u16, h);
}

// v_cvt_pk_bf16_f32: lo -> bits[15:0], hi -> bits[31:16]
__device__ __forceinline__ u32 cvtpk(float lo, float hi) {
  u32 r;
  asm volatile("v_cvt_pk_bf16_f32 %0, %1, %2" : "=v"(r) : "v"(lo), "v"(hi));
  return r;
}

// ---------------- fp32 -> bf16 convert (vectorized) ----------------
__global__ __launch_bounds__(256) void cvt_kernel(const float* __restrict__ src,
                                                  u16* __restrict__ dst, int n4) {
  int i = blockIdx.x * blockDim.x + threadIdx.x;
  int stride = gridDim.x * blockDim.x;
  for (; i < n4; i += stride) {
    float4 f = ((const float4*)src)[i];
    ushort4 o;
    o.x = f2b(f.x); o.y = f2b(f.y); o.z = f2b(f.z); o.w = f2b(f.w);
    ((ushort4*)dst)[i] = o;
  }
}

// ---------------- transpose + convert both weights (merged) ----------------
// y < 48: W_attn[1024][3072] -> Wat[3072][1024];  y >= 48: W_proj -> Wpt.
__global__ __launch_bounds__(256) void tr_cvt2(const float* __restrict__ Wa,
                                               u16* __restrict__ Wat,
                                               const float* __restrict__ Wp,
                                               u16* __restrict__ Wpt) {
  __shared__ u16 tile[64][72];   // +8 pad
  const bool attn = (blockIdx.y < 48);
  const float* src = attn ? Wa : Wp;
  u16* dst = attn ? Wat : Wpt;
  const int N = attn ? N3_ : C_;
  int k0 = blockIdx.x * 64, n0 = (attn ? blockIdx.y : blockIdx.y - 48) * 64;
  #pragma unroll
  for (int t = 0; t < 16; ++t) {
    int idx = threadIdx.x + t * 256;
    int r = idx >> 6, c = idx & 63;
    tile[r][c] = f2b(src[(size_t)(k0 + r) * N + n0 + c]);
  }
  __syncthreads();
  #pragma unroll
  for (int t = 0; t < 16; ++t) {
    int idx = threadIdx.x + t * 256;
    int r = idx >> 6, c = idx & 63;       // r = local n, c = local k
    dst[(size_t)(n0 + r) * C_ + k0 + c] = tile[c][r];
  }
}

// ---------------- GEMM: C[M][N] = A[M][K] * Bt[N][K]^T + bias ----------------
// BM=256 x BN=128, BK=32, 4 waves each owning 128x64 (acc 8x4) -- the bigger
// per-wave tile cuts LDS read amplification: round-18 diagnosis showed the
// 64x64/wave version is LDS-BANDWIDTH-bound (reads 2x tile + writes 1x
// saturate 112 B/cyc/CU). 128x64/wave: reads/KFLOP drop 32.8 -> 22.9.
// 2-buffer ping-pong (48KB -> 2 blocks/CU), ONE barrier per K-step:
// stage(t+1) at the TOP into buf^1 (reads of it finished before the
// PREVIOUS barrier -> race-free); 12 frag ds_reads; 32 MFMA; vmcnt(0)
// (loads issued a full iter earlier) + single s_barrier.
// Granule-XOR swizzle mod 4 (both sides; proven rounds 10-13).
// NOTE: no occupancy bound >2: acc 8x4 = 128 f32/lane; forcing more
// waves/SIMD spills (round-17 lesson).
// EPI 0: scatter to q (scaled) / k / v^T.  EPI 1: fp32 out [M][N].
template <int EPI>
__global__ __launch_bounds__(256, 2) void gemm_bt(const u16* __restrict__ A,
                                                  const u16* __restrict__ Bt,
                                                  const float* __restrict__ bias,
                                                  int K, int N,
                                                  u16* __restrict__ out_qkv,
                                                  float* __restrict__ out_f) {
  __shared__ __align__(16) u16 As[2][256 * 32];
  __shared__ __align__(16) u16 Bs[2][128 * 32];
  const int tid = threadIdx.x;
  const int wave = tid >> 6, lane = tid & 63;
  const int lr = lane & 15, lk = lane >> 4;

  const int m0 = blockIdx.x * 256, n0 = blockIdx.y * 128;
  const int wr = (wave >> 1) * 128, wc = (wave & 1) * 64;

  f32x4 acc[8][4] = {};

  auto stage = [&](int buf, int it) {            // 6 gloads/thread (4 A + 2 B)
    const int kt = it * 32;
    #pragma unroll
    for (int i = 0; i < 4; ++i) {
      int ch = i * 256 + tid;                    // A: 1024 chunks (256r x 4g)
      int row = ch >> 2;
      int gsrc = (ch & 3) ^ ((row >> 1) & 3);
      __builtin_amdgcn_global_load_lds((gptr_t)(A + (size_t)(m0 + row) * K + kt + gsrc * 8),
                                       (sptr_t)(&As[buf][ch * 8]), 16, 0, 0);
    }
    #pragma unroll
    for (int i = 0; i < 2; ++i) {
      int ch = i * 256 + tid;                    // B: 512 chunks (128r x 4g)
      int row = ch >> 2;
      int gsrc = (ch & 3) ^ ((row >> 1) & 3);
      __builtin_amdgcn_global_load_lds((gptr_t)(Bt + (size_t)(n0 + row) * K + kt + gsrc * 8),
                                       (sptr_t)(&Bs[buf][ch * 8]), 16, 0, 0);
    }
  };

  const int KI = K / 32;                         // 32 iters (K=1024)
  stage(0, 0);
  asm volatile("s_waitcnt vmcnt(0)" ::: "memory");
  __builtin_amdgcn_s_barrier();

  for (int it = 0; it < KI; ++it) {
    const int cur = it & 1;
    if (it + 1 < KI) stage(cur ^ 1, it + 1);     // other buffer: no conflict
                                                 // with this iter's reads

    // ---- read frags of tile t (12 ds_read_b128); compiler schedules ----
    bf16x8 af[8], bfr[4];
    #pragma unroll
    for (int mi = 0; mi < 8; ++mi) {
      int r = wr + mi * 16 + lr;
      af[mi] = *(const bf16x8*)(&As[cur][r * 32 + ((lk ^ ((r >> 1) & 3)) << 3)]);
    }
    #pragma unroll
    for (int ni = 0; ni < 4; ++ni) {
      int r = wc + ni * 16 + lr;
      bfr[ni] = *(const bf16x8*)(&Bs[cur][r * 32 + ((lk ^ ((r >> 1) & 3)) << 3)]);
    }

    __builtin_amdgcn_s_setprio(1);
    #pragma unroll
    for (int mi = 0; mi < 8; ++mi)
      #pragma unroll
      for (int ni = 0; ni < 4; ++ni)
        acc[mi][ni] = __builtin_amdgcn_mfma_f32_16x16x32_bf16(af[mi], bfr[ni], acc[mi][ni], 0, 0, 0);
    __builtin_amdgcn_s_setprio(0);

    // ---- tile boundary: t+1's loads were issued a full iter ago ----
    asm volatile("s_waitcnt vmcnt(0)" ::: "memory");
    __builtin_amdgcn_s_barrier();
  }

  if (EPI == 0) {
    const int sel = (n0 >> 10);                   // whole block same q/k/v segment
    #pragma unroll
    for (int mi = 0; mi < 8; ++mi) {
      #pragma unroll
      for (int ni = 0; ni < 4; ++ni) {
        int m = m0 + wr + mi * 16 + lk * 4;       // +j
        int n = n0 + wc + ni * 16 + lr;
        int rem = n & 1023, h = rem >> 6, d = rem & 63;
        int b = m >> 11, t = m & 2047;
        if (sel == 2) {                           // v^T: t contiguous -> ushort4
          ushort4 st;
          #pragma unroll
          for (int j = 0; j < 4; ++j)
            ((u16*)&st)[j] = f2b(acc[mi][ni][j] + bias[n]);
          *(ushort4*)(out_qkv + 2 * (size_t)QKVSZ +
                      (((size_t)(b * H_ + h) * HD_ + d) * T_ + t)) = st;
        } else {
          #pragma unroll
          for (int j = 0; j < 4; ++j) {
            float val = acc[mi][ni][j] + bias[n];
            if (sel == 0) val *= QSCALE;
            out_qkv[(size_t)sel * QKVSZ +
                    (((size_t)(b * H_ + h) * T_ + (t + j)) * HD_ + d)] = f2b(val);
          }
        }
      }
    }
  } else {
    #pragma unroll
    for (int mi = 0; mi < 8; ++mi)
      #pragma unroll
      for (int ni = 0; ni < 4; ++ni)
        #pragma unroll
        for (int j = 0; j < 4; ++j) {
          int m = m0 + wr + mi * 16 + lk * 4 + j;
          int n = n0 + wc + ni * 16 + lr;
          out_f[(size_t)m * C_ + n] = acc[mi][ni][j] + bias[n];
        }
  }
}

// ---------------- causal flash attention ----------------
// 256 threads = 4 waves; q-tile 128 (wave w owns q-rows [BQ+32w, BQ+32w+32)).
// grid (bh=64, 16 q-tiles) = 1024 blocks, heavy-first -> 4 blocks/CU ALL
// resident = 16 waves/CU. K/V staged once per block serves 4 waves.
// 32x32x16 MFMAs, swapped S^T = mfma(K,Q). Softmax per-lane: raw v_exp_f32,
// tree max + TREE sum (depth 5), shfl_xor(32) reduce, defer-max.
// P in registers via cvt_pk + permlane32_swap. O^T = mfma(Vt, P).
// Granule swizzle (row&7)^((row>>3)&3) on BOTH sides.
__global__ __launch_bounds__(256, 4) void attn_k(const u16* __restrict__ q,
                                                 const u16* __restrict__ k,
                                                 const u16* __restrict__ vt,
                                                 u16* __restrict__ y) {
  __shared__ __align__(16) u16 Ks[2][64 * 64];
  __shared__ __align__(16) u16 Vs[2][64 * 64];
  const int tid = threadIdx.x;
  const int wave = tid >> 6, lane = tid & 63;
  const int hi = lane >> 5, lq = lane & 31;
  const int qtb = gridDim.y - 1 - blockIdx.y;    // 15..0, heavy first
  const int bh = blockIdx.x;                     // fastest dim -> XCD spread
  const size_t koff = (size_t)bh * T_ * HD_;     // q,k: [bh][t][d]
  const size_t voff = (size_t)bh * HD_ * T_;     // vt:  [bh][d][t]
  const int qrow = qtb * 128 + 32 * wave + lq;   // this lane's q row (global)
  const int sw = (lq & 7) ^ ((lq >> 3) & 3);     // read-granule swizzle (row=32kh+lq)

  // Q B-frags (pre-scaled by 0.125*log2e): qf[c] = Q[qrow][16c+8hi .. +8]
  bf16x8 qf[4];
  #pragma unroll
  for (int c = 0; c < 4; ++c)
    qf[c] = *(const bf16x8*)(q + koff + (size_t)qrow * HD_ + 16 * c + 8 * hi);

  f32x16 o[2] = {};                              // [dh]: O^T rows 32dh..
  float mrun = -1e30f, lsum = 0.f;

  auto stage = [&](int buf, int kt) {
    const u16* kb = k + koff + (size_t)kt * 64 * HD_;
    const u16* vb = vt + voff + (size_t)kt * 64;
    #pragma unroll
    for (int j = 0; j < 2; ++j) {
      int cb = j * 256 + wave * 64;              // wave-uniform chunk base
      int ch = cb + lane;
      int row = ch >> 3, gg = ch & 7;
      int src = gg ^ (row & 7) ^ ((row >> 3) & 3);   // pre-swizzled source
      __builtin_amdgcn_global_load_lds((gptr_t)(kb + row * HD_ + src * 8),
                                       (sptr_t)(&Ks[buf][cb * 8]), 16, 0, 0);
      __builtin_amdgcn_global_load_lds((gptr_t)(vb + (size_t)row * T_ + src * 8),
                                       (sptr_t)(&Vs[buf][cb * 8]), 16, 0, 0);
    }
  };

  const int nt = 2 * qtb + 2;
  stage(0, 0);
  __syncthreads();

  for (int kt = 0; kt < nt; ++kt) {
    const int cur = kt & 1;
    if (kt + 1 < nt) stage(cur ^ 1, kt + 1);
    const bool active = (kt <= 2 * qtb + (wave >> 1));
    if (active) {
      const bool dia = (kt == 2 * qtb + (wave >> 1));
      const bool skip1 = dia && ((wave & 1) == 0);   // kh=1 fully masked
      const u16* Kb = &Ks[cur][0];
      const u16* Vb = &Vs[cur][0];

      // ---- S^T = K Q^T ----
      f32x16 s[2] = {};
      __builtin_amdgcn_s_setprio(1);
      #pragma unroll
      for (int c = 0; c < 4; ++c) {
        #pragma unroll
        for (int kh = 0; kh < 2; ++kh) {
          if (kh == 1 && skip1) continue;
          int row = 32 * kh + lq;
          bf16x8 kf = *(const bf16x8*)(Kb + row * 64 + (((2 * c + hi) ^ sw) << 3));
          s[kh] = __builtin_amdgcn_mfma_f32_32x32x16_bf16(kf, qf[c], s[kh], 0, 0, 0);
        }
      }
      __builtin_amdgcn_s_setprio(0);

      if (dia) {
        #pragma unroll
        for (int rr = 0; rr < 16; ++rr) {
          int kg = 64 * kt + 4 * hi + (rr & 3) + 8 * (rr >> 2);
          if ((wave & 1) == 0) { if (kg > qrow)      s[0][rr] = -1e30f; }
          else                 { if (kg + 32 > qrow) s[1][rr] = -1e30f; }
        }
      }

      // ---- online softmax (lane and lane^32 share a q-row) ----
      float g0, g1, g2, g3;
      {
        const f32x16& a = s[0];
        g0 = fmaxf(fmaxf(a[0], a[1]),   fmaxf(a[2], a[3]));
        g1 = fmaxf(fmaxf(a[4], a[5]),   fmaxf(a[6], a[7]));
        g2 = fmaxf(fmaxf(a[8], a[9]),   fmaxf(a[10], a[11]));
        g3 = fmaxf(fmaxf(a[12], a[13]), fmaxf(a[14], a[15]));
      }
      if (!skip1) {
        const f32x16& a = s[1];
        g0 = fmaxf(g0, fmaxf(fmaxf(a[0], a[1]),   fmaxf(a[2], a[3])));
        g1 = fmaxf(g1, fmaxf(fmaxf(a[4], a[5]),   fmaxf(a[6], a[7])));
        g2 = fmaxf(g2, fmaxf(fmaxf(a[8], a[9]),   fmaxf(a[10], a[11])));
        g3 = fmaxf(g3, fmaxf(fmaxf(a[12], a[13]), fmaxf(a[14], a[15])));
      }
      float tm = fmaxf(fmaxf(g0, g1), fmaxf(g2, g3));
      tm = fmaxf(tm, __shfl_xor(tm, 32));
      if (__any(tm > mrun + 8.f)) {              // defer-max (T13)
        float mn = fmaxf(mrun, tm);
        float al = __builtin_amdgcn_exp2f(mrun - mn);
        lsum *= al;
        o[0] *= al;
        o[1] *= al;
        mrun = mn;
      }
      // exp + tree sum (depth ~5 instead of serial 32-add chain)
      float rs;
      {
        #pragma unroll
        for (int rr = 0; rr < 16; ++rr)
          s[0][rr] = __builtin_amdgcn_exp2f(s[0][rr] - mrun);
        if (!skip1) {
          #pragma unroll
          for (int rr = 0; rr < 16; ++rr)
            s[1][rr] = __builtin_amdgcn_exp2f(s[1][rr] - mrun);
        }
        const f32x16& a = s[0];
        float t0 = ((a[0] + a[1]) + (a[2] + a[3])) + ((a[4] + a[5]) + (a[6] + a[7]));
        float t1 = ((a[8] + a[9]) + (a[10] + a[11])) + ((a[12] + a[13]) + (a[14] + a[15]));
        rs = t0 + t1;
        if (!skip1) {
          const f32x16& bq = s[1];
          float t2 = ((bq[0] + bq[1]) + (bq[2] + bq[3])) + ((bq[4] + bq[5]) + (bq[6] + bq[7]));
          float t3 = ((bq[8] + bq[9]) + (bq[10] + bq[11])) + ((bq[12] + bq[13]) + (bq[14] + bq[15]));
          rs += t2 + t3;
        }
      }
      rs += __shfl_xor(rs, 32);
      lsum += rs;

      // ---- PV: O^T[d][q] += Vt P (P assembled in-register) ----
      #pragma unroll
      for (int kh = 0; kh < 2; ++kh) {
        if (kh == 1 && skip1) continue;
        bf16x8 pf[2];
        #pragma unroll
        for (int ct = 0; ct < 2; ++ct) {
          u32 A0 = cvtpk(s[kh][8 * ct + 0], s[kh][8 * ct + 1]);
          u32 A1 = cvtpk(s[kh][8 * ct + 2], s[kh][8 * ct + 3]);
          u32 B0 = cvtpk(s[kh][8 * ct + 4], s[kh][8 * ct + 5]);
          u32 B1 = cvtpk(s[kh][8 * ct + 6], s[kh][8 * ct + 7]);
          i32x2 r0 = __builtin_amdgcn_permlane32_swap((int)A0, (int)B0, false, false);
          i32x2 r1 = __builtin_amdgcn_permlane32_swap((int)A1, (int)B1, false, false);
          u32x4 w = {(u32)r0[0], (u32)r1[0], (u32)r0[1], (u32)r1[1]};
          pf[ct] = __builtin_bit_cast(bf16x8, w);
        }
        __builtin_amdgcn_s_setprio(1);
        #pragma unroll
        for (int ct = 0; ct < 2; ++ct)
          #pragma unroll
          for (int dh = 0; dh < 2; ++dh) {
            int row = 32 * dh + lq;
            bf16x8 vf = *(const bf16x8*)(Vb + row * 64 + (((4 * kh + 2 * ct + hi) ^ sw) << 3));
            o[dh] = __builtin_amdgcn_mfma_f32_32x32x16_bf16(vf, pf[ct], o[dh], 0, 0, 0);
          }
        __builtin_amdgcn_s_setprio(0);
      }
    }
    __syncthreads();
  }

  // ---- epilogue: y[b,t,h*64+d] = O^T[d][q] / l ----
  const int b = bh >> 4, h = bh & 15;
  float li = 1.0f / lsum;
  u16* yrow = y + (size_t)(b * T_ + qrow) * C_ + h * 64;
  #pragma unroll
  for (int dh = 0; dh < 2; ++dh)
    #pragma unroll
    for (int u = 0; u < 4; ++u) {
      ushort4 st;
      st.x = f2b(o[dh][4 * u + 0] * li);
      st.y = f2b(o[dh][4 * u + 1] * li);
      st.z = f2b(o[dh][4 * u + 2] * li);
      st.w = f2b(o[dh][4 * u + 3] * li);
      *(ushort4*)(yrow + 32 * dh + 8 * u + 4 * hi) = st;
    }
}

extern "C" void kernel_launch(void* const* d_in, const int* in_sizes, int n_in,
                              void* d_out, int out_size, void* d_ws, size_t ws_size,
                              hipStream_t stream) {
  const float* x      = (const float*)d_in[0];
  const float* W_attn = (const float*)d_in[1];
  const float* b_attn = (const float*)d_in[2];
  const float* W_proj = (const float*)d_in[3];
  const float* b_proj = (const float*)d_in[4];
  float* out = (float*)d_out;

  u16* ws = (u16*)d_ws;
  u16* xb  = ws;
  u16* Wat = xb + (size_t)M_ * C_;
  u16* Wpt = Wat + (size_t)N3_ * C_;
  u16* qkv = Wpt + (size_t)C_ * C_;
  u16* y   = qkv + (size_t)3 * QKVSZ;

  cvt_kernel<<<2048, 256, 0, stream>>>(x, xb, M_ * C_ / 4);
  tr_cvt2<<<dim3(C_ / 64, 64), 256, 0, stream>>>(W_attn, Wat, W_proj, Wpt);
  gemm_bt<0><<<dim3(M_ / 256, N3_ / 128), 256, 0, stream>>>(xb, Wat, b_attn, C_, N3_, qkv, nullptr);
  attn_k<<<dim3(B_ * H_, T_ / 128), 256, 0, stream>>>(qkv, qkv + QKVSZ, qkv + 2 * QKVSZ, y);
  gemm_bt<1><<<dim3(M_ / 256, C_ / 128), 256, 0, stream>>>(y, Wpt, b_proj, C_, C_, nullptr, out);
}

// Round 20
// 166.617 us; speedup vs baseline: 1.1240x; 1.1240x over previous
//
#include <hip/hip_runtime.h>
#include <hip/hip_bf16.h>

#define B_ 4
#define T_ 2048
#define C_ 1024
#define H_ 16
#define HD_ 64
#define M_ (B_*T_)        // 8192 rows
#define N3_ (3*C_)        // 3072
#define QKVSZ (B_*H_*T_*HD_)  // 8388608 elems per tensor
#define QSCALE 0.1803368801f  // 0.125 * log2(e)

typedef unsigned short u16;
typedef unsigned int u32;
typedef __attribute__((ext_vector_type(8))) __bf16 bf16x8;
typedef __attribute__((ext_vector_type(4))) float f32x4;
typedef __attribute__((ext_vector_type(16))) float f32x16;
typedef __attribute__((ext_vector_type(2))) int i32x2;
typedef __attribute__((ext_vector_type(4))) u32 u32x4;
typedef const __attribute__((address_space(1))) void* gptr_t;
typedef __attribute__((address_space(3))) void* sptr_t;

__device__ __forceinline__ u16 f2b(float f) {
  __hip_bfloat16 h = __float2bfloat16(f);
  return __builtin_bit_cast(u16, h);
}

// v_cvt_pk_bf16_f32: lo -> bits[15:0], hi -> bits[31:16]
__device__ __forceinline__ u32 cvtpk(float lo, float hi) {
  u32 r;
  asm volatile("v_cvt_pk_bf16_f32 %0, %1, %2" : "=v"(r) : "v"(lo), "v"(hi));
  return r;
}

// ---------------- fp32 -> bf16 convert (vectorized) ----------------
__global__ __launch_bounds__(256) void cvt_kernel(const float* __restrict__ src,
                                                  u16* __restrict__ dst, int n4) {
  int i = blockIdx.x * blockDim.x + threadIdx.x;
  int stride = gridDim.x * blockDim.x;
  for (; i < n4; i += stride) {
    float4 f = ((const float4*)src)[i];
    ushort4 o;
    o.x = f2b(f.x); o.y = f2b(f.y); o.z = f2b(f.z); o.w = f2b(f.w);
    ((ushort4*)dst)[i] = o;
  }
}

// ---------------- transpose + convert both weights (merged) ----------------
// y < 48: W_attn[1024][3072] -> Wat[3072][1024];  y >= 48: W_proj -> Wpt.
__global__ __launch_bounds__(256) void tr_cvt2(const float* __restrict__ Wa,
                                               u16* __restrict__ Wat,
                                               const float* __restrict__ Wp,
                                               u16* __restrict__ Wpt) {
  __shared__ u16 tile[64][72];   // +8 pad
  const bool attn = (blockIdx.y < 48);
  const float* src = attn ? Wa : Wp;
  u16* dst = attn ? Wat : Wpt;
  const int N = attn ? N3_ : C_;
  int k0 = blockIdx.x * 64, n0 = (attn ? blockIdx.y : blockIdx.y - 48) * 64;
  #pragma unroll
  for (int t = 0; t < 16; ++t) {
    int idx = threadIdx.x + t * 256;
    int r = idx >> 6, c = idx & 63;
    tile[r][c] = f2b(src[(size_t)(k0 + r) * N + n0 + c]);
  }
  __syncthreads();
  #pragma unroll
  for (int t = 0; t < 16; ++t) {
    int idx = threadIdx.x + t * 256;
    int r = idx >> 6, c = idx & 63;       // r = local n, c = local k
    dst[(size_t)(n0 + r) * C_ + k0 + c] = tile[c][r];
  }
}

// ---------------- GEMM: C[M][N] = A[M][K] * Bt[N][K]^T + bias ----------------
// BM=128 x BN=128, BK=64, 4 waves (2x2), per-wave 64x64 (acc 4x4).
// 2-buffer ping-pong, ONE barrier per K-step: stage(t+1) issues at the TOP
// into buf^1 (reads of it finished before the PREVIOUS barrier -> race-free).
// 16 frag ds_reads (compiler-scheduled lgkmcnt), 32 MFMA in two k-half
// clusters, vmcnt(0) (issued a full iter earlier -> residual wait only) +
// single s_barrier. Granule-XOR swizzle mod 8 (both sides).
// VERIFIED LOCAL OPTIMUM (rounds 14-19): bigger tile (256x128) -> LDS-amp
// win swamped by 2x barrier events + tail (r19: 84us); occupancy bound >2
// -> accumulator spill (r17: 165us); BK=32 -> +5us barriers (r13 vs r14).
// EPI 0: scatter to q (scaled) / k / v^T.  EPI 1: fp32 out [M][N].
template <int EPI>
__global__ __launch_bounds__(256, 2) void gemm_bt(const u16* __restrict__ A,
                                                  const u16* __restrict__ Bt,
                                                  const float* __restrict__ bias,
                                                  int K, int N,
                                                  u16* __restrict__ out_qkv,
                                                  float* __restrict__ out_f) {
  __shared__ __align__(16) u16 As[2][128 * 64];
  __shared__ __align__(16) u16 Bs[2][128 * 64];
  const int tid = threadIdx.x;
  const int wave = tid >> 6, lane = tid & 63;
  const int lr = lane & 15, lk = lane >> 4;

  const int m0 = blockIdx.x * 128, n0 = blockIdx.y * 128;
  const int wr = (wave >> 1) * 64, wc = (wave & 1) * 64;

  f32x4 acc[4][4] = {};

  auto stage = [&](int buf, int it) {            // 8 gloads/thread (4 A + 4 B)
    const int kt = it * 64;
    #pragma unroll
    for (int i = 0; i < 4; ++i) {
      int ch = i * 256 + tid;                    // A: 1024 chunks (128r x 8g)
      int row = ch >> 3;
      int gsrc = (ch & 7) ^ (row & 7);
      __builtin_amdgcn_global_load_lds((gptr_t)(A + (size_t)(m0 + row) * K + kt + gsrc * 8),
                                       (sptr_t)(&As[buf][ch * 8]), 16, 0, 0);
    }
    #pragma unroll
    for (int i = 0; i < 4; ++i) {
      int ch = i * 256 + tid;                    // B: 1024 chunks
      int row = ch >> 3;
      int gsrc = (ch & 7) ^ (row & 7);
      __builtin_amdgcn_global_load_lds((gptr_t)(Bt + (size_t)(n0 + row) * K + kt + gsrc * 8),
                                       (sptr_t)(&Bs[buf][ch * 8]), 16, 0, 0);
    }
  };

  const int KI = K / 64;                         // 16 iters (K=1024)
  stage(0, 0);
  asm volatile("s_waitcnt vmcnt(0)" ::: "memory");
  __builtin_amdgcn_s_barrier();

  for (int it = 0; it < KI; ++it) {
    const int cur = it & 1;
    if (it + 1 < KI) stage(cur ^ 1, it + 1);     // into buffer freed 1 barrier ago

    // ---- two k-half clusters: read 8 frags, 16 MFMA each ----
    #pragma unroll
    for (int h = 0; h < 2; ++h) {
      bf16x8 af[4], bfr[4];
      #pragma unroll
      for (int mi = 0; mi < 4; ++mi) {
        int r = wr + mi * 16 + lr;
        af[mi] = *(const bf16x8*)(&As[cur][r * 64 + (((4 * h + lk) ^ (r & 7)) << 3)]);
      }
      #pragma unroll
      for (int ni = 0; ni < 4; ++ni) {
        int r = wc + ni * 16 + lr;
        bfr[ni] = *(const bf16x8*)(&Bs[cur][r * 64 + (((4 * h + lk) ^ (r & 7)) << 3)]);
      }
      __builtin_amdgcn_s_setprio(1);
      #pragma unroll
      for (int mi = 0; mi < 4; ++mi)
        #pragma unroll
        for (int ni = 0; ni < 4; ++ni)
          acc[mi][ni] = __builtin_amdgcn_mfma_f32_16x16x32_bf16(af[mi], bfr[ni], acc[mi][ni], 0, 0, 0);
      __builtin_amdgcn_s_setprio(0);
    }

    // ---- tile boundary: t+1's loads were issued a full iter ago ----
    asm volatile("s_waitcnt vmcnt(0)" ::: "memory");
    __builtin_amdgcn_s_barrier();
  }

  if (EPI == 0) {
    const int sel = (n0 >> 10);                   // whole block same q/k/v segment
    #pragma unroll
    for (int mi = 0; mi < 4; ++mi) {
      #pragma unroll
      for (int ni = 0; ni < 4; ++ni) {
        int m = m0 + wr + mi * 16 + lk * 4;       // +j
        int n = n0 + wc + ni * 16 + lr;
        int rem = n & 1023, h = rem >> 6, d = rem & 63;
        int b = m >> 11, t = m & 2047;
        if (sel == 2) {                           // v^T: t contiguous -> ushort4
          ushort4 st;
          #pragma unroll
          for (int j = 0; j < 4; ++j)
            ((u16*)&st)[j] = f2b(acc[mi][ni][j] + bias[n]);
          *(ushort4*)(out_qkv + 2 * (size_t)QKVSZ +
                      (((size_t)(b * H_ + h) * HD_ + d) * T_ + t)) = st;
        } else {
          #pragma unroll
          for (int j = 0; j < 4; ++j) {
            float val = acc[mi][ni][j] + bias[n];
            if (sel == 0) val *= QSCALE;
            out_qkv[(size_t)sel * QKVSZ +
                    (((size_t)(b * H_ + h) * T_ + (t + j)) * HD_ + d)] = f2b(val);
          }
        }
      }
    }
  } else {
    #pragma unroll
    for (int mi = 0; mi < 4; ++mi)
      #pragma unroll
      for (int ni = 0; ni < 4; ++ni)
        #pragma unroll
        for (int j = 0; j < 4; ++j) {
          int m = m0 + wr + mi * 16 + lk * 4 + j;
          int n = n0 + wc + ni * 16 + lr;
          out_f[(size_t)m * C_ + n] = acc[mi][ni][j] + bias[n];
        }
  }
}

// ---------------- causal flash attention ----------------
// 256 threads = 4 waves; q-tile 128 (wave w owns q-rows [BQ+32w, BQ+32w+32)).
// grid (bh=64, 16 q-tiles) = 1024 blocks, heavy-first -> 4 blocks/CU ALL
// resident = 16 waves/CU. K/V staged once per block serves 4 waves.
// 32x32x16 MFMAs, swapped S^T = mfma(K,Q). Softmax per-lane: raw v_exp_f32,
// tree max + TREE sum (depth 5), shfl_xor(32) reduce, defer-max.
// P in registers via cvt_pk + permlane32_swap. O^T = mfma(Vt, P).
// Granule swizzle (row&7)^((row>>3)&3) on BOTH sides.
__global__ __launch_bounds__(256, 4) void attn_k(const u16* __restrict__ q,
                                                 const u16* __restrict__ k,
                                                 const u16* __restrict__ vt,
                                                 u16* __restrict__ y) {
  __shared__ __align__(16) u16 Ks[2][64 * 64];
  __shared__ __align__(16) u16 Vs[2][64 * 64];
  const int tid = threadIdx.x;
  const int wave = tid >> 6, lane = tid & 63;
  const int hi = lane >> 5, lq = lane & 31;
  const int qtb = gridDim.y - 1 - blockIdx.y;    // 15..0, heavy first
  const int bh = blockIdx.x;                     // fastest dim -> XCD spread
  const size_t koff = (size_t)bh * T_ * HD_;     // q,k: [bh][t][d]
  const size_t voff = (size_t)bh * HD_ * T_;     // vt:  [bh][d][t]
  const int qrow = qtb * 128 + 32 * wave + lq;   // this lane's q row (global)
  const int sw = (lq & 7) ^ ((lq >> 3) & 3);     // read-granule swizzle (row=32kh+lq)

  // Q B-frags (pre-scaled by 0.125*log2e): qf[c] = Q[qrow][16c+8hi .. +8]
  bf16x8 qf[4];
  #pragma unroll
  for (int c = 0; c < 4; ++c)
    qf[c] = *(const bf16x8*)(q + koff + (size_t)qrow * HD_ + 16 * c + 8 * hi);

  f32x16 o[2] = {};                              // [dh]: O^T rows 32dh..
  float mrun = -1e30f, lsum = 0.f;

  auto stage = [&](int buf, int kt) {
    const u16* kb = k + koff + (size_t)kt * 64 * HD_;
    const u16* vb = vt + voff + (size_t)kt * 64;
    #pragma unroll
    for (int j = 0; j < 2; ++j) {
      int cb = j * 256 + wave * 64;              // wave-uniform chunk base
      int ch = cb + lane;
      int row = ch >> 3, gg = ch & 7;
      int src = gg ^ (row & 7) ^ ((row >> 3) & 3);   // pre-swizzled source
      __builtin_amdgcn_global_load_lds((gptr_t)(kb + row * HD_ + src * 8),
                                       (sptr_t)(&Ks[buf][cb * 8]), 16, 0, 0);
      __builtin_amdgcn_global_load_lds((gptr_t)(vb + (size_t)row * T_ + src * 8),
                                       (sptr_t)(&Vs[buf][cb * 8]), 16, 0, 0);
    }
  };

  const int nt = 2 * qtb + 2;
  stage(0, 0);
  __syncthreads();

  for (int kt = 0; kt < nt; ++kt) {
    const int cur = kt & 1;
    if (kt + 1 < nt) stage(cur ^ 1, kt + 1);
    const bool active = (kt <= 2 * qtb + (wave >> 1));
    if (active) {
      const bool dia = (kt == 2 * qtb + (wave >> 1));
      const bool skip1 = dia && ((wave & 1) == 0);   // kh=1 fully masked
      const u16* Kb = &Ks[cur][0];
      const u16* Vb = &Vs[cur][0];

      // ---- S^T = K Q^T ----
      f32x16 s[2] = {};
      __builtin_amdgcn_s_setprio(1);
      #pragma unroll
      for (int c = 0; c < 4; ++c) {
        #pragma unroll
        for (int kh = 0; kh < 2; ++kh) {
          if (kh == 1 && skip1) continue;
          int row = 32 * kh + lq;
          bf16x8 kf = *(const bf16x8*)(Kb + row * 64 + (((2 * c + hi) ^ sw) << 3));
          s[kh] = __builtin_amdgcn_mfma_f32_32x32x16_bf16(kf, qf[c], s[kh], 0, 0, 0);
        }
      }
      __builtin_amdgcn_s_setprio(0);

      if (dia) {
        #pragma unroll
        for (int rr = 0; rr < 16; ++rr) {
          int kg = 64 * kt + 4 * hi + (rr & 3) + 8 * (rr >> 2);
          if ((wave & 1) == 0) { if (kg > qrow)      s[0][rr] = -1e30f; }
          else                 { if (kg + 32 > qrow) s[1][rr] = -1e30f; }
        }
      }

      // ---- online softmax (lane and lane^32 share a q-row) ----
      float g0, g1, g2, g3;
      {
        const f32x16& a = s[0];
        g0 = fmaxf(fmaxf(a[0], a[1]),   fmaxf(a[2], a[3]));
        g1 = fmaxf(fmaxf(a[4], a[5]),   fmaxf(a[6], a[7]));
        g2 = fmaxf(fmaxf(a[8], a[9]),   fmaxf(a[10], a[11]));
        g3 = fmaxf(fmaxf(a[12], a[13]), fmaxf(a[14], a[15]));
      }
      if (!skip1) {
        const f32x16& a = s[1];
        g0 = fmaxf(g0, fmaxf(fmaxf(a[0], a[1]),   fmaxf(a[2], a[3])));
        g1 = fmaxf(g1, fmaxf(fmaxf(a[4], a[5]),   fmaxf(a[6], a[7])));
        g2 = fmaxf(g2, fmaxf(fmaxf(a[8], a[9]),   fmaxf(a[10], a[11])));
        g3 = fmaxf(g3, fmaxf(fmaxf(a[12], a[13]), fmaxf(a[14], a[15])));
      }
      float tm = fmaxf(fmaxf(g0, g1), fmaxf(g2, g3));
      tm = fmaxf(tm, __shfl_xor(tm, 32));
      if (__any(tm > mrun + 8.f)) {              // defer-max (T13)
        float mn = fmaxf(mrun, tm);
        float al = __builtin_amdgcn_exp2f(mrun - mn);
        lsum *= al;
        o[0] *= al;
        o[1] *= al;
        mrun = mn;
      }
      // exp + tree sum (depth ~5 instead of serial 32-add chain)
      float rs;
      {
        #pragma unroll
        for (int rr = 0; rr < 16; ++rr)
          s[0][rr] = __builtin_amdgcn_exp2f(s[0][rr] - mrun);
        if (!skip1) {
          #pragma unroll
          for (int rr = 0; rr < 16; ++rr)
            s[1][rr] = __builtin_amdgcn_exp2f(s[1][rr] - mrun);
        }
        const f32x16& a = s[0];
        float t0 = ((a[0] + a[1]) + (a[2] + a[3])) + ((a[4] + a[5]) + (a[6] + a[7]));
        float t1 = ((a[8] + a[9]) + (a[10] + a[11])) + ((a[12] + a[13]) + (a[14] + a[15]));
        rs = t0 + t1;
        if (!skip1) {
          const f32x16& bq = s[1];
          float t2 = ((bq[0] + bq[1]) + (bq[2] + bq[3])) + ((bq[4] + bq[5]) + (bq[6] + bq[7]));
          float t3 = ((bq[8] + bq[9]) + (bq[10] + bq[11])) + ((bq[12] + bq[13]) + (bq[14] + bq[15]));
          rs += t2 + t3;
        }
      }
      rs += __shfl_xor(rs, 32);
      lsum += rs;

      // ---- PV: O^T[d][q] += Vt P (P assembled in-register) ----
      #pragma unroll
      for (int kh = 0; kh < 2; ++kh) {
        if (kh == 1 && skip1) continue;
        bf16x8 pf[2];
        #pragma unroll
        for (int ct = 0; ct < 2; ++ct) {
          u32 A0 = cvtpk(s[kh][8 * ct + 0], s[kh][8 * ct + 1]);
          u32 A1 = cvtpk(s[kh][8 * ct + 2], s[kh][8 * ct + 3]);
          u32 B0 = cvtpk(s[kh][8 * ct + 4], s[kh][8 * ct + 5]);
          u32 B1 = cvtpk(s[kh][8 * ct + 6], s[kh][8 * ct + 7]);
          i32x2 r0 = __builtin_amdgcn_permlane32_swap((int)A0, (int)B0, false, false);
          i32x2 r1 = __builtin_amdgcn_permlane32_swap((int)A1, (int)B1, false, false);
          u32x4 w = {(u32)r0[0], (u32)r1[0], (u32)r0[1], (u32)r1[1]};
          pf[ct] = __builtin_bit_cast(bf16x8, w);
        }
        __builtin_amdgcn_s_setprio(1);
        #pragma unroll
        for (int ct = 0; ct < 2; ++ct)
          #pragma unroll
          for (int dh = 0; dh < 2; ++dh) {
            int row = 32 * dh + lq;
            bf16x8 vf = *(const bf16x8*)(Vb + row * 64 + (((4 * kh + 2 * ct + hi) ^ sw) << 3));
            o[dh] = __builtin_amdgcn_mfma_f32_32x32x16_bf16(vf, pf[ct], o[dh], 0, 0, 0);
          }
        __builtin_amdgcn_s_setprio(0);
      }
    }
    __syncthreads();
  }

  // ---- epilogue: y[b,t,h*64+d] = O^T[d][q] / l ----
  const int b = bh >> 4, h = bh & 15;
  float li = 1.0f / lsum;
  u16* yrow = y + (size_t)(b * T_ + qrow) * C_ + h * 64;
  #pragma unroll
  for (int dh = 0; dh < 2; ++dh)
    #pragma unroll
    for (int u = 0; u < 4; ++u) {
      ushort4 st;
      st.x = f2b(o[dh][4 * u + 0] * li);
      st.y = f2b(o[dh][4 * u + 1] * li);
      st.z = f2b(o[dh][4 * u + 2] * li);
      st.w = f2b(o[dh][4 * u + 3] * li);
      *(ushort4*)(yrow + 32 * dh + 8 * u + 4 * hi) = st;
    }
}

extern "C" void kernel_launch(void* const* d_in, const int* in_sizes, int n_in,
                              void* d_out, int out_size, void* d_ws, size_t ws_size,
                              hipStream_t stream) {
  const float* x      = (const float*)d_in[0];
  const float* W_attn = (const float*)d_in[1];
  const float* b_attn = (const float*)d_in[2];
  const float* W_proj = (const float*)d_in[3];
  const float* b_proj = (const float*)d_in[4];
  float* out = (float*)d_out;

  u16* ws = (u16*)d_ws;
  u16* xb  = ws;
  u16* Wat = xb + (size_t)M_ * C_;
  u16* Wpt = Wat + (size_t)N3_ * C_;
  u16* qkv = Wpt + (size_t)C_ * C_;
  u16* y   = qkv + (size_t)3 * QKVSZ;

  cvt_kernel<<<2048, 256, 0, stream>>>(x, xb, M_ * C_ / 4);
  tr_cvt2<<<dim3(C_ / 64, 64), 256, 0, stream>>>(W_attn, Wat, W_proj, Wpt);
  gemm_bt<0><<<dim3(M_ / 128, N3_ / 128), 256, 0, stream>>>(xb, Wat, b_attn, C_, N3_, qkv, nullptr);
  attn_k<<<dim3(B_ * H_, T_ / 128), 256, 0, stream>>>(qkv, qkv + QKVSZ, qkv + 2 * QKVSZ, y);
  gemm_bt<1><<<dim3(M_ / 128, C_ / 128), 256, 0, stream>>>(y, Wpt, b_proj, C_, C_, nullptr, out);
}

// Round 21
// 164.396 us; speedup vs baseline: 1.1392x; 1.0135x over previous
//
#include <hip/hip_runtime.h>
#include <hip/hip_bf16.h>

#define B_ 4
#define T_ 2048
#define C_ 1024
#define H_ 16
#define HD_ 64
#define M_ (B_*T_)        // 8192 rows
#define N3_ (3*C_)        // 3072
#define QKVSZ (B_*H_*T_*HD_)  // 8388608 elems per tensor
#define QSCALE 0.1803368801f  // 0.125 * log2(e)

typedef unsigned short u16;
typedef unsigned int u32;
typedef __attribute__((ext_vector_type(8))) __bf16 bf16x8;
typedef __attribute__((ext_vector_type(4))) float f32x4;
typedef __attribute__((ext_vector_type(16))) float f32x16;
typedef __attribute__((ext_vector_type(2))) int i32x2;
typedef __attribute__((ext_vector_type(4))) u32 u32x4;
typedef const __attribute__((address_space(1))) void* gptr_t;
typedef __attribute__((address_space(3))) void* sptr_t;

__device__ __forceinline__ u16 f2b(float f) {
  __hip_bfloat16 h = __float2bfloat16(f);
  return __builtin_bit_cast(u16, h);
}

// v_cvt_pk_bf16_f32: lo -> bits[15:0], hi -> bits[31:16]
__device__ __forceinline__ u32 cvtpk(float lo, float hi) {
  u32 r;
  asm volatile("v_cvt_pk_bf16_f32 %0, %1, %2" : "=v"(r) : "v"(lo), "v"(hi));
  return r;
}

// ---------------- merged prep: x->bf16 convert + both weight transposes ----
// blocks [0,2048): grid-stride fp32->bf16 convert of x (float4/ushort4).
// blocks [2048,3072): 64x64 transpose+convert tiles; bb&15 = k-block,
// bb>>4 < 48 -> W_attn column, else W_proj. Branch is blockIdx-uniform.
__global__ __launch_bounds__(256) void prep_k(const float* __restrict__ x,
                                              u16* __restrict__ xb,
                                              const float* __restrict__ Wa,
                                              u16* __restrict__ Wat,
                                              const float* __restrict__ Wp,
                                              u16* __restrict__ Wpt) {
  __shared__ u16 tile[64][72];   // +8 pad (tr branch only)
  const int bx = blockIdx.x;
  if (bx < 2048) {
    const int n4 = M_ * C_ / 4;
    const int stride = 2048 * 256;
    for (int i = bx * 256 + threadIdx.x; i < n4; i += stride) {
      float4 f = ((const float4*)x)[i];
      ushort4 o;
      o.x = f2b(f.x); o.y = f2b(f.y); o.z = f2b(f.z); o.w = f2b(f.w);
      ((ushort4*)xb)[i] = o;
    }
  } else {
    const int bb = bx - 2048;            // 0..1023
    const int kblk = bb & 15;            // C_/64 = 16 k-blocks
    const int nblk = bb >> 4;            // 0..63 output-column blocks
    const bool attn = (nblk < 48);
    const float* src = attn ? Wa : Wp;
    u16* dst = attn ? Wat : Wpt;
    const int N = attn ? N3_ : C_;
    const int k0 = kblk * 64, n0 = (attn ? nblk : nblk - 48) * 64;
    #pragma unroll
    for (int t = 0; t < 16; ++t) {
      int idx = threadIdx.x + t * 256;
      int r = idx >> 6, c = idx & 63;
      tile[r][c] = f2b(src[(size_t)(k0 + r) * N + n0 + c]);
    }
    __syncthreads();
    #pragma unroll
    for (int t = 0; t < 16; ++t) {
      int idx = threadIdx.x + t * 256;
      int r = idx >> 6, c = idx & 63;    // r = local n, c = local k
      dst[(size_t)(n0 + r) * C_ + k0 + c] = tile[c][r];
    }
  }
}

// ---------------- GEMM: C[M][N] = A[M][K] * Bt[N][K]^T + bias ----------------
// BM=128 x BN=128, BK=64, 4 waves (2x2), per-wave 64x64 (acc 4x4).
// 2-buffer ping-pong, ONE barrier per K-step: stage(t+1) issues at the TOP
// into buf^1 (reads of it finished before the PREVIOUS barrier -> race-free).
// 16 frag ds_reads (compiler-scheduled lgkmcnt), 32 MFMA in two k-half
// clusters, vmcnt(0) (issued a full iter earlier -> residual wait only) +
// single s_barrier. Granule-XOR swizzle mod 8 (both sides).
// VERIFIED LOCAL OPTIMUM (rounds 14-19): bigger tile (256x128) -> LDS-amp
// win swamped by 2x barrier events + tail (r19: 84us); occupancy bound >2
// -> accumulator spill (r17: 165us); BK=32 -> +5us barriers (r13 vs r14).
// EPI 0: scatter to q (scaled) / k / v^T.  EPI 1: fp32 out [M][N].
template <int EPI>
__global__ __launch_bounds__(256, 2) void gemm_bt(const u16* __restrict__ A,
                                                  const u16* __restrict__ Bt,
                                                  const float* __restrict__ bias,
                                                  int K, int N,
                                                  u16* __restrict__ out_qkv,
                                                  float* __restrict__ out_f) {
  __shared__ __align__(16) u16 As[2][128 * 64];
  __shared__ __align__(16) u16 Bs[2][128 * 64];
  const int tid = threadIdx.x;
  const int wave = tid >> 6, lane = tid & 63;
  const int lr = lane & 15, lk = lane >> 4;

  const int m0 = blockIdx.x * 128, n0 = blockIdx.y * 128;
  const int wr = (wave >> 1) * 64, wc = (wave & 1) * 64;

  f32x4 acc[4][4] = {};

  auto stage = [&](int buf, int it) {            // 8 gloads/thread (4 A + 4 B)
    const int kt = it * 64;
    #pragma unroll
    for (int i = 0; i < 4; ++i) {
      int ch = i * 256 + tid;                    // A: 1024 chunks (128r x 8g)
      int row = ch >> 3;
      int gsrc = (ch & 7) ^ (row & 7);
      __builtin_amdgcn_global_load_lds((gptr_t)(A + (size_t)(m0 + row) * K + kt + gsrc * 8),
                                       (sptr_t)(&As[buf][ch * 8]), 16, 0, 0);
    }
    #pragma unroll
    for (int i = 0; i < 4; ++i) {
      int ch = i * 256 + tid;                    // B: 1024 chunks
      int row = ch >> 3;
      int gsrc = (ch & 7) ^ (row & 7);
      __builtin_amdgcn_global_load_lds((gptr_t)(Bt + (size_t)(n0 + row) * K + kt + gsrc * 8),
                                       (sptr_t)(&Bs[buf][ch * 8]), 16, 0, 0);
    }
  };

  const int KI = K / 64;                         // 16 iters (K=1024)
  stage(0, 0);
  asm volatile("s_waitcnt vmcnt(0)" ::: "memory");
  __builtin_amdgcn_s_barrier();

  for (int it = 0; it < KI; ++it) {
    const int cur = it & 1;
    if (it + 1 < KI) stage(cur ^ 1, it + 1);     // into buffer freed 1 barrier ago

    // ---- two k-half clusters: read 8 frags, 16 MFMA each ----
    #pragma unroll
    for (int h = 0; h < 2; ++h) {
      bf16x8 af[4], bfr[4];
      #pragma unroll
      for (int mi = 0; mi < 4; ++mi) {
        int r = wr + mi * 16 + lr;
        af[mi] = *(const bf16x8*)(&As[cur][r * 64 + (((4 * h + lk) ^ (r & 7)) << 3)]);
      }
      #pragma unroll
      for (int ni = 0; ni < 4; ++ni) {
        int r = wc + ni * 16 + lr;
        bfr[ni] = *(const bf16x8*)(&Bs[cur][r * 64 + (((4 * h + lk) ^ (r & 7)) << 3)]);
      }
      __builtin_amdgcn_s_setprio(1);
      #pragma unroll
      for (int mi = 0; mi < 4; ++mi)
        #pragma unroll
        for (int ni = 0; ni < 4; ++ni)
          acc[mi][ni] = __builtin_amdgcn_mfma_f32_16x16x32_bf16(af[mi], bfr[ni], acc[mi][ni], 0, 0, 0);
      __builtin_amdgcn_s_setprio(0);
    }

    // ---- tile boundary: t+1's loads were issued a full iter ago ----
    asm volatile("s_waitcnt vmcnt(0)" ::: "memory");
    __builtin_amdgcn_s_barrier();
  }

  if (EPI == 0) {
    const int sel = (n0 >> 10);                   // whole block same q/k/v segment
    #pragma unroll
    for (int mi = 0; mi < 4; ++mi) {
      #pragma unroll
      for (int ni = 0; ni < 4; ++ni) {
        int m = m0 + wr + mi * 16 + lk * 4;       // +j
        int n = n0 + wc + ni * 16 + lr;
        int rem = n & 1023, h = rem >> 6, d = rem & 63;
        int b = m >> 11, t = m & 2047;
        if (sel == 2) {                           // v^T: t contiguous -> ushort4
          ushort4 st;
          #pragma unroll
          for (int j = 0; j < 4; ++j)
            ((u16*)&st)[j] = f2b(acc[mi][ni][j] + bias[n]);
          *(ushort4*)(out_qkv + 2 * (size_t)QKVSZ +
                      (((size_t)(b * H_ + h) * HD_ + d) * T_ + t)) = st;
        } else {
          #pragma unroll
          for (int j = 0; j < 4; ++j) {
            float val = acc[mi][ni][j] + bias[n];
            if (sel == 0) val *= QSCALE;
            out_qkv[(size_t)sel * QKVSZ +
                    (((size_t)(b * H_ + h) * T_ + (t + j)) * HD_ + d)] = f2b(val);
          }
        }
      }
    }
  } else {
    #pragma unroll
    for (int mi = 0; mi < 4; ++mi)
      #pragma unroll
      for (int ni = 0; ni < 4; ++ni)
        #pragma unroll
        for (int j = 0; j < 4; ++j) {
          int m = m0 + wr + mi * 16 + lk * 4 + j;
          int n = n0 + wc + ni * 16 + lr;
          out_f[(size_t)m * C_ + n] = acc[mi][ni][j] + bias[n];
        }
  }
}

// ---------------- causal flash attention ----------------
// 256 threads = 4 waves; q-tile 128 (wave w owns q-rows [BQ+32w, BQ+32w+32)).
// grid (bh=64, 16 q-tiles) = 1024 blocks, heavy-first -> 4 blocks/CU ALL
// resident = 16 waves/CU. K/V staged once per block serves 4 waves.
// 32x32x16 MFMAs, swapped S^T = mfma(K,Q). Softmax per-lane: raw v_exp_f32,
// tree max + TREE sum (depth 5), shfl_xor(32) reduce, defer-max.
// P in registers via cvt_pk + permlane32_swap. O^T = mfma(Vt, P).
// Granule swizzle (row&7)^((row>>3)&3) on BOTH sides.
__global__ __launch_bounds__(256, 4) void attn_k(const u16* __restrict__ q,
                                                 const u16* __restrict__ k,
                                                 const u16* __restrict__ vt,
                                                 u16* __restrict__ y) {
  __shared__ __align__(16) u16 Ks[2][64 * 64];
  __shared__ __align__(16) u16 Vs[2][64 * 64];
  const int tid = threadIdx.x;
  const int wave = tid >> 6, lane = tid & 63;
  const int hi = lane >> 5, lq = lane & 31;
  const int qtb = gridDim.y - 1 - blockIdx.y;    // 15..0, heavy first
  const int bh = blockIdx.x;                     // fastest dim -> XCD spread
  const size_t koff = (size_t)bh * T_ * HD_;     // q,k: [bh][t][d]
  const size_t voff = (size_t)bh * HD_ * T_;     // vt:  [bh][d][t]
  const int qrow = qtb * 128 + 32 * wave + lq;   // this lane's q row (global)
  const int sw = (lq & 7) ^ ((lq >> 3) & 3);     // read-granule swizzle (row=32kh+lq)

  // Q B-frags (pre-scaled by 0.125*log2e): qf[c] = Q[qrow][16c+8hi .. +8]
  bf16x8 qf[4];
  #pragma unroll
  for (int c = 0; c < 4; ++c)
    qf[c] = *(const bf16x8*)(q + koff + (size_t)qrow * HD_ + 16 * c + 8 * hi);

  f32x16 o[2] = {};                              // [dh]: O^T rows 32dh..
  float mrun = -1e30f, lsum = 0.f;

  auto stage = [&](int buf, int kt) {
    const u16* kb = k + koff + (size_t)kt * 64 * HD_;
    const u16* vb = vt + voff + (size_t)kt * 64;
    #pragma unroll
    for (int j = 0; j < 2; ++j) {
      int cb = j * 256 + wave * 64;              // wave-uniform chunk base
      int ch = cb + lane;
      int row = ch >> 3, gg = ch & 7;
      int src = gg ^ (row & 7) ^ ((row >> 3) & 3);   // pre-swizzled source
      __builtin_amdgcn_global_load_lds((gptr_t)(kb + row * HD_ + src * 8),
                                       (sptr_t)(&Ks[buf][cb * 8]), 16, 0, 0);
      __builtin_amdgcn_global_load_lds((gptr_t)(vb + (size_t)row * T_ + src * 8),
                                       (sptr_t)(&Vs[buf][cb * 8]), 16, 0, 0);
    }
  };

  const int nt = 2 * qtb + 2;
  stage(0, 0);
  __syncthreads();

  for (int kt = 0; kt < nt; ++kt) {
    const int cur = kt & 1;
    if (kt + 1 < nt) stage(cur ^ 1, kt + 1);
    const bool active = (kt <= 2 * qtb + (wave >> 1));
    if (active) {
      const bool dia = (kt == 2 * qtb + (wave >> 1));
      const bool skip1 = dia && ((wave & 1) == 0);   // kh=1 fully masked
      const u16* Kb = &Ks[cur][0];
      const u16* Vb = &Vs[cur][0];

      // ---- S^T = K Q^T ----
      f32x16 s[2] = {};
      __builtin_amdgcn_s_setprio(1);
      #pragma unroll
      for (int c = 0; c < 4; ++c) {
        #pragma unroll
        for (int kh = 0; kh < 2; ++kh) {
          if (kh == 1 && skip1) continue;
          int row = 32 * kh + lq;
          bf16x8 kf = *(const bf16x8*)(Kb + row * 64 + (((2 * c + hi) ^ sw) << 3));
          s[kh] = __builtin_amdgcn_mfma_f32_32x32x16_bf16(kf, qf[c], s[kh], 0, 0, 0);
        }
      }
      __builtin_amdgcn_s_setprio(0);

      if (dia) {
        #pragma unroll
        for (int rr = 0; rr < 16; ++rr) {
          int kg = 64 * kt + 4 * hi + (rr & 3) + 8 * (rr >> 2);
          if ((wave & 1) == 0) { if (kg > qrow)      s[0][rr] = -1e30f; }
          else                 { if (kg + 32 > qrow) s[1][rr] = -1e30f; }
        }
      }

      // ---- online softmax (lane and lane^32 share a q-row) ----
      float g0, g1, g2, g3;
      {
        const f32x16& a = s[0];
        g0 = fmaxf(fmaxf(a[0], a[1]),   fmaxf(a[2], a[3]));
        g1 = fmaxf(fmaxf(a[4], a[5]),   fmaxf(a[6], a[7]));
        g2 = fmaxf(fmaxf(a[8], a[9]),   fmaxf(a[10], a[11]));
        g3 = fmaxf(fmaxf(a[12], a[13]), fmaxf(a[14], a[15]));
      }
      if (!skip1) {
        const f32x16& a = s[1];
        g0 = fmaxf(g0, fmaxf(fmaxf(a[0], a[1]),   fmaxf(a[2], a[3])));
        g1 = fmaxf(g1, fmaxf(fmaxf(a[4], a[5]),   fmaxf(a[6], a[7])));
        g2 = fmaxf(g2, fmaxf(fmaxf(a[8], a[9]),   fmaxf(a[10], a[11])));
        g3 = fmaxf(g3, fmaxf(fmaxf(a[12], a[13]), fmaxf(a[14], a[15])));
      }
      float tm = fmaxf(fmaxf(g0, g1), fmaxf(g2, g3));
      tm = fmaxf(tm, __shfl_xor(tm, 32));
      if (__any(tm > mrun + 8.f)) {              // defer-max (T13)
        float mn = fmaxf(mrun, tm);
        float al = __builtin_amdgcn_exp2f(mrun - mn);
        lsum *= al;
        o[0] *= al;
        o[1] *= al;
        mrun = mn;
      }
      // exp + tree sum (depth ~5 instead of serial 32-add chain)
      float rs;
      {
        #pragma unroll
        for (int rr = 0; rr < 16; ++rr)
          s[0][rr] = __builtin_amdgcn_exp2f(s[0][rr] - mrun);
        if (!skip1) {
          #pragma unroll
          for (int rr = 0; rr < 16; ++rr)
            s[1][rr] = __builtin_amdgcn_exp2f(s[1][rr] - mrun);
        }
        const f32x16& a = s[0];
        float t0 = ((a[0] + a[1]) + (a[2] + a[3])) + ((a[4] + a[5]) + (a[6] + a[7]));
        float t1 = ((a[8] + a[9]) + (a[10] + a[11])) + ((a[12] + a[13]) + (a[14] + a[15]));
        rs = t0 + t1;
        if (!skip1) {
          const f32x16& bq = s[1];
          float t2 = ((bq[0] + bq[1]) + (bq[2] + bq[3])) + ((bq[4] + bq[5]) + (bq[6] + bq[7]));
          float t3 = ((bq[8] + bq[9]) + (bq[10] + bq[11])) + ((bq[12] + bq[13]) + (bq[14] + bq[15]));
          rs += t2 + t3;
        }
      }
      rs += __shfl_xor(rs, 32);
      lsum += rs;

      // ---- PV: O^T[d][q] += Vt P (P assembled in-register) ----
      #pragma unroll
      for (int kh = 0; kh < 2; ++kh) {
        if (kh == 1 && skip1) continue;
        bf16x8 pf[2];
        #pragma unroll
        for (int ct = 0; ct < 2; ++ct) {
          u32 A0 = cvtpk(s[kh][8 * ct + 0], s[kh][8 * ct + 1]);
          u32 A1 = cvtpk(s[kh][8 * ct + 2], s[kh][8 * ct + 3]);
          u32 B0 = cvtpk(s[kh][8 * ct + 4], s[kh][8 * ct + 5]);
          u32 B1 = cvtpk(s[kh][8 * ct + 6], s[kh][8 * ct + 7]);
          i32x2 r0 = __builtin_amdgcn_permlane32_swap((int)A0, (int)B0, false, false);
          i32x2 r1 = __builtin_amdgcn_permlane32_swap((int)A1, (int)B1, false, false);
          u32x4 w = {(u32)r0[0], (u32)r1[0], (u32)r0[1], (u32)r1[1]};
          pf[ct] = __builtin_bit_cast(bf16x8, w);
        }
        __builtin_amdgcn_s_setprio(1);
        #pragma unroll
        for (int ct = 0; ct < 2; ++ct)
          #pragma unroll
          for (int dh = 0; dh < 2; ++dh) {
            int row = 32 * dh + lq;
            bf16x8 vf = *(const bf16x8*)(Vb + row * 64 + (((4 * kh + 2 * ct + hi) ^ sw) << 3));
            o[dh] = __builtin_amdgcn_mfma_f32_32x32x16_bf16(vf, pf[ct], o[dh], 0, 0, 0);
          }
        __builtin_amdgcn_s_setprio(0);
      }
    }
    __syncthreads();
  }

  // ---- epilogue: y[b,t,h*64+d] = O^T[d][q] / l ----
  const int b = bh >> 4, h = bh & 15;
  float li = 1.0f / lsum;
  u16* yrow = y + (size_t)(b * T_ + qrow) * C_ + h * 64;
  #pragma unroll
  for (int dh = 0; dh < 2; ++dh)
    #pragma unroll
    for (int u = 0; u < 4; ++u) {
      ushort4 st;
      st.x = f2b(o[dh][4 * u + 0] * li);
      st.y = f2b(o[dh][4 * u + 1] * li);
      st.z = f2b(o[dh][4 * u + 2] * li);
      st.w = f2b(o[dh][4 * u + 3] * li);
      *(ushort4*)(yrow + 32 * dh + 8 * u + 4 * hi) = st;
    }
}

extern "C" void kernel_launch(void* const* d_in, const int* in_sizes, int n_in,
                              void* d_out, int out_size, void* d_ws, size_t ws_size,
                              hipStream_t stream) {
  const float* x      = (const float*)d_in[0];
  const float* W_attn = (const float*)d_in[1];
  const float* b_attn = (const float*)d_in[2];
  const float* W_proj = (const float*)d_in[3];
  const float* b_proj = (const float*)d_in[4];
  float* out = (float*)d_out;

  u16* ws = (u16*)d_ws;
  u16* xb  = ws;
  u16* Wat = xb + (size_t)M_ * C_;
  u16* Wpt = Wat + (size_t)N3_ * C_;
  u16* qkv = Wpt + (size_t)C_ * C_;
  u16* y   = qkv + (size_t)3 * QKVSZ;

  prep_k<<<3072, 256, 0, stream>>>(x, xb, W_attn, Wat, W_proj, Wpt);
  gemm_bt<0><<<dim3(M_ / 128, N3_ / 128), 256, 0, stream>>>(xb, Wat, b_attn, C_, N3_, qkv, nullptr);
  attn_k<<<dim3(B_ * H_, T_ / 128), 256, 0, stream>>>(qkv, qkv + QKVSZ, qkv + 2 * QKVSZ, y);
  gemm_bt<1><<<dim3(M_ / 128, C_ / 128), 256, 0, stream>>>(y, Wpt, b_proj, C_, C_, nullptr, out);
}